// Round 1
// 569.708 us; speedup vs baseline: 1.1089x; 1.1089x over previous
//
#include <hip/hip_runtime.h>
#include <hip/hip_bf16.h>

#define S_DIM 1024
#define INNER 32
#define PAIR  128
#define LSEQ  1024

typedef float f2 __attribute__((ext_vector_type(2)));

// ---------------------------------------------------------------------------
// Kernel 1: per-row LayerNorm + projection to 64 (q|k), plus the separable
// "diff" term precomputation: Aq = q @ W2, Ak = k @ W2  (W2 = o_w[32:64,:]).
// One block per sequence row. 256 threads.
// ---------------------------------------------------------------------------
__global__ __launch_bounds__(256) void ln_proj_kernel(
    const float* __restrict__ x,      // (1024, 1024)
    const float* __restrict__ gamma,  // (1024)
    const float* __restrict__ beta,   // (1024)
    const float* __restrict__ pw,     // (1024, 64)
    const float* __restrict__ pb,     // (64)
    const float* __restrict__ ow,     // (64, 128)
    float* __restrict__ qk,           // (1024, 64)  q=cols 0..31, k=cols 32..63
    float* __restrict__ Aq,           // (1024, 128)
    float* __restrict__ Ak)           // (1024, 128)
{
    const int row  = blockIdx.x;
    const int t    = threadIdx.x;
    const int lane = t & 63;
    const int wv   = t >> 6;

    __shared__ float s_sh[S_DIM];
    __shared__ float wsum[4], wsum2[4];
    __shared__ float hpart[4][64];
    __shared__ float h_sh[64];

    // --- load 4 elements per thread, accumulate sums ---
    float4 xv = ((const float4*)(x + (size_t)row * S_DIM))[t];
    float sum = xv.x + xv.y + xv.z + xv.w;
    float sq  = xv.x*xv.x + xv.y*xv.y + xv.z*xv.z + xv.w*xv.w;
    #pragma unroll
    for (int off = 32; off; off >>= 1) {
        sum += __shfl_down(sum, off, 64);
        sq  += __shfl_down(sq,  off, 64);
    }
    if (lane == 0) { wsum[wv] = sum; wsum2[wv] = sq; }
    __syncthreads();
    float tot  = wsum[0] + wsum[1] + wsum[2] + wsum[3];
    float tot2 = wsum2[0] + wsum2[1] + wsum2[2] + wsum2[3];
    float mu   = tot * (1.0f / S_DIM);
    float var  = tot2 * (1.0f / S_DIM) - mu * mu;
    float rstd = rsqrtf(var + 1e-5f);

    float4 gv = ((const float4*)gamma)[t];
    float4 bv = ((const float4*)beta)[t];
    float4 sv;
    sv.x = (xv.x - mu) * rstd * gv.x + bv.x;
    sv.y = (xv.y - mu) * rstd * gv.y + bv.y;
    sv.z = (xv.z - mu) * rstd * gv.z + bv.z;
    sv.w = (xv.w - mu) * rstd * gv.w + bv.w;
    ((float4*)s_sh)[t] = sv;
    __syncthreads();

    // --- projection: h[c] = sum_d s[d] * pw[d,c] ; split d over 4 waves ---
    {
        const int c    = lane;     // 0..63 output column
        const int part = wv;       // 0..3
        const int dbase = part * 256;
        const float* pwp = pw + c;
        float acc = 0.f;
        #pragma unroll 8
        for (int d = 0; d < 256; ++d) {
            acc = fmaf(s_sh[dbase + d], pwp[(size_t)(dbase + d) * 64], acc);
        }
        hpart[part][c] = acc;
    }
    __syncthreads();
    if (t < 64) {
        float h = hpart[0][t] + hpart[1][t] + hpart[2][t] + hpart[3][t] + pb[t];
        h_sh[t] = h;
        qk[(size_t)row * 64 + t] = h;
    }
    __syncthreads();

    // --- Aq[row,p] = sum_{c<32} q[c]*W2[c,p] ;  Ak likewise with k ---
    {
        const int p    = t & 127;
        const int half = t >> 7;              // 0 -> Aq, 1 -> Ak
        const float* w2 = ow + 32 * PAIR + p; // W2 base
        const float* hh = h_sh + half * 32;
        float acc = 0.f;
        #pragma unroll
        for (int c = 0; c < 32; ++c)
            acc = fmaf(hh[c], w2[(size_t)c * PAIR], acc);
        if (half == 0) Aq[(size_t)row * PAIR + p] = acc;
        else           Ak[(size_t)row * PAIR + p] = acc;
    }
}

// ---------------------------------------------------------------------------
// Kernel 2: out[i,j,p] = sum_{c<32} q[j,c]*k[i,c]*W1[c,p] + Aq[j,p] - Ak[i,p]
//                        + o_b[p]
// Grid: (1024 i, 8 jblocks). Block: 256 threads = 4 waves; each wave owns
// 32 consecutive j. Each lane owns the packed pair p = {2*lane, 2*lane+1}
// (f2), so the inner fma is v_pk_fma_f32-shaped and the store is one
// dwordx2. Two j per iteration -> 8 independent 16-deep fma chains.
// Nontemporal stores keep the 512 MB write stream out of L2 so the in-loop
// qk/Aq reads stay cached.
// ---------------------------------------------------------------------------
__global__ __launch_bounds__(256) void pair_kernel(
    const float* __restrict__ qk,   // (1024, 64)
    const float* __restrict__ Aq,   // (1024, 128)
    const float* __restrict__ Ak,   // (1024, 128)
    const float* __restrict__ ow,   // (64, 128); W1 = rows 0..31
    const float* __restrict__ ob,   // (128)
    float* __restrict__ out)        // (1024, 1024, 128)
{
    const int i    = blockIdx.x;
    const int jblk = blockIdx.y;
    const int lane = threadIdx.x & 63;
    const int wv   = threadIdx.x >> 6;

    // kw[c] = k[i,c] * W1[c, {2*lane, 2*lane+1}]
    f2 kw[32];
    {
        const float4* k4 = (const float4*)(qk + (size_t)i * 64 + 32);
        #pragma unroll
        for (int c4 = 0; c4 < 8; ++c4) {
            float4 kv = k4[c4];
            const f2* w1a = (const f2*)(ow + (size_t)(c4*4+0) * PAIR);
            const f2* w1b = (const f2*)(ow + (size_t)(c4*4+1) * PAIR);
            const f2* w1c = (const f2*)(ow + (size_t)(c4*4+2) * PAIR);
            const f2* w1d = (const f2*)(ow + (size_t)(c4*4+3) * PAIR);
            kw[c4*4+0] = kv.x * w1a[lane];
            kw[c4*4+1] = kv.y * w1b[lane];
            kw[c4*4+2] = kv.z * w1c[lane];
            kw[c4*4+3] = kv.w * w1d[lane];
        }
    }

    const f2 bias = ((const f2*)ob)[lane] - ((const f2*)(Ak + (size_t)i * PAIR))[lane];
    const f2* Aq2 = (const f2*)Aq;
    f2* out2 = (f2*)out;

    const int jbase = jblk * 128 + wv * 32;
    #pragma unroll 2
    for (int jj = 0; jj < 32; jj += 2) {
        const int j0 = __builtin_amdgcn_readfirstlane(jbase + jj);
        const int j1 = j0 + 1;
        const float4* q40 = (const float4*)(qk + (size_t)j0 * 64);
        const float4* q41 = (const float4*)(qk + (size_t)j1 * 64);

        f2 a0 = bias + Aq2[(size_t)j0 * 64 + lane];
        f2 a1 = bias + Aq2[(size_t)j1 * 64 + lane];
        f2 b0 = {0.f, 0.f};
        f2 b1 = {0.f, 0.f};

        #pragma unroll
        for (int c4 = 0; c4 < 4; ++c4) {
            float4 qv0 = q40[c4];
            float4 qv1 = q41[c4];
            a0 += qv0.x * kw[c4*4+0];  a1 += qv1.x * kw[c4*4+0];
            a0 += qv0.y * kw[c4*4+1];  a1 += qv1.y * kw[c4*4+1];
            a0 += qv0.z * kw[c4*4+2];  a1 += qv1.z * kw[c4*4+2];
            a0 += qv0.w * kw[c4*4+3];  a1 += qv1.w * kw[c4*4+3];
        }
        #pragma unroll
        for (int c4 = 4; c4 < 8; ++c4) {
            float4 qv0 = q40[c4];
            float4 qv1 = q41[c4];
            b0 += qv0.x * kw[c4*4+0];  b1 += qv1.x * kw[c4*4+0];
            b0 += qv0.y * kw[c4*4+1];  b1 += qv1.y * kw[c4*4+1];
            b0 += qv0.z * kw[c4*4+2];  b1 += qv1.z * kw[c4*4+2];
            b0 += qv0.w * kw[c4*4+3];  b1 += qv1.w * kw[c4*4+3];
        }
        a0 += b0;
        a1 += b1;

        const size_t off0 = ((size_t)i * LSEQ + (size_t)j0) * (PAIR / 2);
        __builtin_nontemporal_store(a0, out2 + off0 + lane);
        __builtin_nontemporal_store(a1, out2 + off0 + 64 + lane);
    }
}

extern "C" void kernel_launch(void* const* d_in, const int* in_sizes, int n_in,
                              void* d_out, int out_size, void* d_ws, size_t ws_size,
                              hipStream_t stream) {
    const float* x     = (const float*)d_in[0];
    const float* gamma = (const float*)d_in[1];
    const float* beta  = (const float*)d_in[2];
    const float* pw    = (const float*)d_in[3];
    const float* pb    = (const float*)d_in[4];
    const float* ow    = (const float*)d_in[5];
    const float* ob    = (const float*)d_in[6];
    float* out = (float*)d_out;

    // workspace layout
    float* qk = (float*)d_ws;                 // 1024*64  = 256 KB
    float* Aq = qk + (size_t)LSEQ * 64;       // 1024*128 = 512 KB
    float* Ak = Aq + (size_t)LSEQ * PAIR;     // 1024*128 = 512 KB

    ln_proj_kernel<<<dim3(LSEQ), dim3(256), 0, stream>>>(
        x, gamma, beta, pw, pb, ow, qk, Aq, Ak);

    pair_kernel<<<dim3(LSEQ, 8), dim3(256), 0, stream>>>(
        qk, Aq, Ak, ow, ob, out);
}

// Round 2
// 566.752 us; speedup vs baseline: 1.1147x; 1.0052x over previous
//
#include <hip/hip_runtime.h>
#include <hip/hip_bf16.h>

#define S_DIM 1024
#define INNER 32
#define PAIR  128
#define LSEQ  1024

typedef float f2 __attribute__((ext_vector_type(2)));

// ---------------------------------------------------------------------------
// Kernel 1: per-row LayerNorm + projection to 64 (q|k), plus the separable
// "diff" term precomputation: Aq = q @ W2, Ak = k @ W2  (W2 = o_w[32:64,:]).
// One block per sequence row. 256 threads.
// ---------------------------------------------------------------------------
__global__ __launch_bounds__(256) void ln_proj_kernel(
    const float* __restrict__ x,      // (1024, 1024)
    const float* __restrict__ gamma,  // (1024)
    const float* __restrict__ beta,   // (1024)
    const float* __restrict__ pw,     // (1024, 64)
    const float* __restrict__ pb,     // (64)
    const float* __restrict__ ow,     // (64, 128)
    float* __restrict__ qk,           // (1024, 64)  q=cols 0..31, k=cols 32..63
    float* __restrict__ Aq,           // (1024, 128)
    float* __restrict__ Ak)           // (1024, 128)
{
    const int row  = blockIdx.x;
    const int t    = threadIdx.x;
    const int lane = t & 63;
    const int wv   = t >> 6;

    __shared__ float s_sh[S_DIM];
    __shared__ float wsum[4], wsum2[4];
    __shared__ float hpart[4][64];
    __shared__ float h_sh[64];

    // --- load 4 elements per thread, accumulate sums ---
    float4 xv = ((const float4*)(x + (size_t)row * S_DIM))[t];
    float sum = xv.x + xv.y + xv.z + xv.w;
    float sq  = xv.x*xv.x + xv.y*xv.y + xv.z*xv.z + xv.w*xv.w;
    #pragma unroll
    for (int off = 32; off; off >>= 1) {
        sum += __shfl_down(sum, off, 64);
        sq  += __shfl_down(sq,  off, 64);
    }
    if (lane == 0) { wsum[wv] = sum; wsum2[wv] = sq; }
    __syncthreads();
    float tot  = wsum[0] + wsum[1] + wsum[2] + wsum[3];
    float tot2 = wsum2[0] + wsum2[1] + wsum2[2] + wsum2[3];
    float mu   = tot * (1.0f / S_DIM);
    float var  = tot2 * (1.0f / S_DIM) - mu * mu;
    float rstd = rsqrtf(var + 1e-5f);

    float4 gv = ((const float4*)gamma)[t];
    float4 bv = ((const float4*)beta)[t];
    float4 sv;
    sv.x = (xv.x - mu) * rstd * gv.x + bv.x;
    sv.y = (xv.y - mu) * rstd * gv.y + bv.y;
    sv.z = (xv.z - mu) * rstd * gv.z + bv.z;
    sv.w = (xv.w - mu) * rstd * gv.w + bv.w;
    ((float4*)s_sh)[t] = sv;
    __syncthreads();

    // --- projection: h[c] = sum_d s[d] * pw[d,c] ; split d over 4 waves ---
    {
        const int c    = lane;     // 0..63 output column
        const int part = wv;       // 0..3
        const int dbase = part * 256;
        const float* pwp = pw + c;
        float acc = 0.f;
        #pragma unroll 8
        for (int d = 0; d < 256; ++d) {
            acc = fmaf(s_sh[dbase + d], pwp[(size_t)(dbase + d) * 64], acc);
        }
        hpart[part][c] = acc;
    }
    __syncthreads();
    if (t < 64) {
        float h = hpart[0][t] + hpart[1][t] + hpart[2][t] + hpart[3][t] + pb[t];
        h_sh[t] = h;
        qk[(size_t)row * 64 + t] = h;
    }
    __syncthreads();

    // --- Aq[row,p] = sum_{c<32} q[c]*W2[c,p] ;  Ak likewise with k ---
    {
        const int p    = t & 127;
        const int half = t >> 7;              // 0 -> Aq, 1 -> Ak
        const float* w2 = ow + 32 * PAIR + p; // W2 base
        const float* hh = h_sh + half * 32;
        float acc = 0.f;
        #pragma unroll
        for (int c = 0; c < 32; ++c)
            acc = fmaf(hh[c], w2[(size_t)c * PAIR], acc);
        if (half == 0) Aq[(size_t)row * PAIR + p] = acc;
        else           Ak[(size_t)row * PAIR + p] = acc;
    }
}

// ---------------------------------------------------------------------------
// Kernel 2: out[i,j,p] = sum_{c<32} q[j,c]*k[i,c]*W1[c,p] + Aq[j,p] - Ak[i,p]
//                        + o_b[p]
// Grid: (1024 i, 8 jblocks). Block: 256 threads = 4 waves; each wave owns
// 32 consecutive j. Lane owns packed pair p = {2*lane, 2*lane+1}.
// Depth-2 software pipeline: single-j stages, double-buffered q (uniform
// address -> SGPR s_loads) and Aq (f2 vector load). Stage n consumes buffers
// issued at stage n-2, so L2 latency (~200-300 cyc) hides under ~160 cycles
// of own-wave fma issue x 4 resident waves/SIMD.
// Tail prefetches read <= row 1025 of qk/Aq: still inside the 1.25 MB
// workspace (qk|Aq|Ak are contiguous), values unused.
// ---------------------------------------------------------------------------
__global__ __launch_bounds__(256, 4) void pair_kernel(
    const float* __restrict__ qk,   // (1024, 64)
    const float* __restrict__ Aq,   // (1024, 128)
    const float* __restrict__ Ak,   // (1024, 128)
    const float* __restrict__ ow,   // (64, 128); W1 = rows 0..31
    const float* __restrict__ ob,   // (128)
    float* __restrict__ out)        // (1024, 1024, 128)
{
    const int i    = blockIdx.x;
    const int jblk = blockIdx.y;
    const int lane = threadIdx.x & 63;
    const int wv   = threadIdx.x >> 6;

    // kw[c] = k[i,c] * W1[c, {2*lane, 2*lane+1}]   (64 VGPRs)
    f2 kw[32];
    {
        const float4* k4 = (const float4*)(qk + (size_t)i * 64 + 32);
        #pragma unroll
        for (int c4 = 0; c4 < 8; ++c4) {
            float4 kv = k4[c4];
            const f2* w1a = (const f2*)(ow + (size_t)(c4*4+0) * PAIR);
            const f2* w1b = (const f2*)(ow + (size_t)(c4*4+1) * PAIR);
            const f2* w1c = (const f2*)(ow + (size_t)(c4*4+2) * PAIR);
            const f2* w1d = (const f2*)(ow + (size_t)(c4*4+3) * PAIR);
            kw[c4*4+0] = kv.x * w1a[lane];
            kw[c4*4+1] = kv.y * w1b[lane];
            kw[c4*4+2] = kv.z * w1c[lane];
            kw[c4*4+3] = kv.w * w1d[lane];
        }
    }

    const f2 bias = ((const f2*)ob)[lane] - ((const f2*)(Ak + (size_t)i * PAIR))[lane];
    const f2* Aq2 = (const f2*)Aq;
    f2* out2 = (f2*)out;

    const int jbase = jblk * 128 + wv * 32;
    const int j0    = __builtin_amdgcn_readfirstlane(jbase);
    // per-lane output base (f2 units)
    f2* op = out2 + ((size_t)i * LSEQ + (size_t)j0) * (PAIR / 2) + lane;

    // q row loader: uniform address -> scalar loads into SGPRs
    #define LDQ(buf, row) {                                                  \
        const float4* _s = (const float4*)(qk + (size_t)(row) * 64);         \
        _Pragma("unroll")                                                    \
        for (int _c = 0; _c < 8; ++_c) buf[_c] = _s[_c];                     \
    }

    float4 qa[8], qb[8];
    f2 aqa, aqb;
    LDQ(qa, j0);     aqa = Aq2[(size_t)j0 * 64 + lane];
    LDQ(qb, j0 + 1); aqb = Aq2[(size_t)(j0 + 1) * 64 + lane];

    #pragma unroll 1
    for (int jj = 0; jj < 32; jj += 2) {
        // ---- even stage: row j0+jj, consumes qa/aqa ----
        {
            f2 a = {0.f, 0.f}, b = {0.f, 0.f};
            #pragma unroll
            for (int c4 = 0; c4 < 4; ++c4) {
                float4 q0 = qa[c4];
                float4 q1 = qa[c4 + 4];
                a += q0.x * kw[c4*4+0];   b += q1.x * kw[16 + c4*4+0];
                a += q0.y * kw[c4*4+1];   b += q1.y * kw[16 + c4*4+1];
                a += q0.z * kw[c4*4+2];   b += q1.z * kw[16 + c4*4+2];
                a += q0.w * kw[c4*4+3];   b += q1.w * kw[16 + c4*4+3];
            }
            f2 r = (a + b) + (bias + aqa);
            __builtin_nontemporal_store(r, op + (size_t)jj * (PAIR / 2));
            // prefetch stage jj+2
            LDQ(qa, j0 + jj + 2);
            aqa = Aq2[(size_t)(j0 + jj + 2) * 64 + lane];
        }
        // ---- odd stage: row j0+jj+1, consumes qb/aqb ----
        {
            f2 a = {0.f, 0.f}, b = {0.f, 0.f};
            #pragma unroll
            for (int c4 = 0; c4 < 4; ++c4) {
                float4 q0 = qb[c4];
                float4 q1 = qb[c4 + 4];
                a += q0.x * kw[c4*4+0];   b += q1.x * kw[16 + c4*4+0];
                a += q0.y * kw[c4*4+1];   b += q1.y * kw[16 + c4*4+1];
                a += q0.z * kw[c4*4+2];   b += q1.z * kw[16 + c4*4+2];
                a += q0.w * kw[c4*4+3];   b += q1.w * kw[16 + c4*4+3];
            }
            f2 r = (a + b) + (bias + aqb);
            __builtin_nontemporal_store(r, op + (size_t)(jj + 1) * (PAIR / 2));
            // prefetch stage jj+3
            LDQ(qb, j0 + jj + 3);
            aqb = Aq2[(size_t)(j0 + jj + 3) * 64 + lane];
        }
    }
    #undef LDQ
}

extern "C" void kernel_launch(void* const* d_in, const int* in_sizes, int n_in,
                              void* d_out, int out_size, void* d_ws, size_t ws_size,
                              hipStream_t stream) {
    const float* x     = (const float*)d_in[0];
    const float* gamma = (const float*)d_in[1];
    const float* beta  = (const float*)d_in[2];
    const float* pw    = (const float*)d_in[3];
    const float* pb    = (const float*)d_in[4];
    const float* ow    = (const float*)d_in[5];
    const float* ob    = (const float*)d_in[6];
    float* out = (float*)d_out;

    // workspace layout
    float* qk = (float*)d_ws;                 // 1024*64  = 256 KB
    float* Aq = qk + (size_t)LSEQ * 64;       // 1024*128 = 512 KB
    float* Ak = Aq + (size_t)LSEQ * PAIR;     // 1024*128 = 512 KB

    ln_proj_kernel<<<dim3(LSEQ), dim3(256), 0, stream>>>(
        x, gamma, beta, pw, pb, ow, qk, Aq, Ak);

    pair_kernel<<<dim3(LSEQ, 8), dim3(256), 0, stream>>>(
        qk, Aq, Ak, ow, ob, out);
}